// Round 1
// baseline (438.791 us; speedup 1.0000x reference)
//
#include <hip/hip_runtime.h>

// Attention_44006234915573 — windowed attention, MI355X/gfx950
// B=256, D=128, HEADS=4, DH=32, N=625 (padded to 640), bf16 MFMA pipeline.
//
// ws layout (bytes):
//   [0,   41943040)  Q   bf16 [1024][640][32]   (pre-scaled by SCALE*LOG2E)
//   [+1x, +2x)       K   bf16 [1024][640][32]
//   [+2x, +3x)       Vt  bf16 [1024][32][640]
//   [+3x, +4x)       O   bf16 [256][640][128]   (head-major channels)
//   [+4x, +4x+3.3MB) bias_t bf16 [4][640][640]  = table[idx[i][j]][h]*LOG2E, j>=625 -> -1e30
// total 171,048,960 bytes required of d_ws.

typedef __attribute__((ext_vector_type(8))) short short8;
typedef __attribute__((ext_vector_type(4))) float f32x4;

#define MFMA16(a, b, c) __builtin_amdgcn_mfma_f32_16x16x32_bf16((a), (b), (c), 0, 0, 0)

__device__ __forceinline__ unsigned short f2b(float f) {
  union { float f; unsigned u; } x; x.f = f;
  unsigned r = x.u + 0x7fffu + ((x.u >> 16) & 1u);  // RNE
  return (unsigned short)(r >> 16);
}
__device__ __forceinline__ float b2f(unsigned short s) {
  union { unsigned u; float f; } x; x.u = ((unsigned)s) << 16;
  return x.f;
}

constexpr float LOG2E_F = 1.4426950408889634f;
constexpr float QSCALE  = 0.17677669529663687f * 1.4426950408889634f;  // dh^-0.5 * log2(e)

// ---------------------------------------------------------------- bias expand
__global__ __launch_bounds__(256) void k_bias(const float* __restrict__ table,
                                              const int* __restrict__ idx,
                                              unsigned short* __restrict__ bt) {
  int id = blockIdx.x * 256 + threadIdx.x;  // 0 .. 409599 over (j,i)
  int i = id % 640;
  int j = id / 640;
  float v0, v1, v2, v3;
  if (j >= 625) {
    v0 = v1 = v2 = v3 = -1e30f;             // masks padded K columns via exp2 -> 0
  } else if (i >= 625) {
    v0 = v1 = v2 = v3 = 0.f;                // padded Q rows: harmless finite
  } else {
    int ix = idx[i * 625 + j];
    const float* tr = table + ix * 4;
    v0 = tr[0] * LOG2E_F; v1 = tr[1] * LOG2E_F;
    v2 = tr[2] * LOG2E_F; v3 = tr[3] * LOG2E_F;
  }
  int o = j * 640 + i;
  bt[o]           = f2b(v0);
  bt[409600 + o]  = f2b(v1);
  bt[819200 + o]  = f2b(v2);
  bt[1228800 + o] = f2b(v3);
}

// ---------------------------------------------------------------- QKV proj
// one block per batch; W_qkv staged bf16 in LDS; A = x^T read direct from global
__global__ __launch_bounds__(256) void k_qkv(const float* __restrict__ x,
                                             const float* __restrict__ wqkv,
                                             unsigned short* __restrict__ qws,
                                             unsigned short* __restrict__ kws,
                                             unsigned short* __restrict__ vtws) {
  __shared__ unsigned short Wl[384 * 136];
  int b = blockIdx.x, t = threadIdx.x;
  for (int it = 0; it < 48; ++it) {
    int g4 = it * 256 + t;                  // 12288 float4 of W
    int c = g4 >> 5, d0 = (g4 & 31) << 2;
    float4 w4 = *reinterpret_cast<const float4*>(wqkv + c * 128 + d0);
    ushort4 p;
    p.x = f2b(w4.x); p.y = f2b(w4.y); p.z = f2b(w4.z); p.w = f2b(w4.w);
    *reinterpret_cast<ushort4*>(&Wl[c * 136 + d0]) = p;
  }
  __syncthreads();
  int w = t >> 6, lane = t & 63, r16 = lane & 15, g = lane >> 4;
  for (int tile = 0; tile < 10; ++tile) {
    int nr = tile * 64 + w * 16;            // wave's 16 rows
    int n = nr + r16;
    bool nv = n < 625;
    const float* xb = x + (size_t)b * 80000 + n;
    short8 a[4];
#pragma unroll
    for (int kk = 0; kk < 4; ++kk) {
      short8 av;
#pragma unroll
      for (int jj = 0; jj < 8; ++jj) {
        int d = kk * 32 + g * 8 + jj;
        av[jj] = (short)f2b(nv ? xb[d * 625] : 0.f);
      }
      a[kk] = av;
    }
    f32x4 acc[24];
#pragma unroll
    for (int nf = 0; nf < 24; ++nf) acc[nf] = (f32x4){0.f, 0.f, 0.f, 0.f};
#pragma unroll
    for (int kk = 0; kk < 4; ++kk) {
#pragma unroll
      for (int nf = 0; nf < 24; ++nf) {
        short8 bf = *reinterpret_cast<short8*>(&Wl[(nf * 16 + r16) * 136 + kk * 32 + g * 8]);
        acc[nf] = MFMA16(a[kk], bf, acc[nf]);
      }
    }
#pragma unroll
    for (int nf = 0; nf < 24; ++nf) {
      int c0 = nf * 16;
      int sel = c0 >> 7, hh = (c0 & 127) >> 5, t0 = (c0 & 31);
      float mul = (sel == 0) ? QSCALE : 1.f;
      size_t base = (size_t)(b * 4 + hh);
      if (sel < 2) {
        unsigned short* dst = (sel ? kws : qws) + (base * 640 + nr + 4 * g) * 32 + t0 + r16;
#pragma unroll
        for (int rr = 0; rr < 4; ++rr) dst[rr * 32] = f2b(acc[nf][rr] * mul);
      } else {
        ushort4 pv;
        pv.x = f2b(acc[nf][0]); pv.y = f2b(acc[nf][1]);
        pv.z = f2b(acc[nf][2]); pv.w = f2b(acc[nf][3]);
        *reinterpret_cast<ushort4*>(vtws + (base * 32 + t0 + r16) * 640 + nr + 4 * g) = pv;
      }
    }
  }
}

// ---------------------------------------------------------------- attention
// one block per (b,h); K + V^T staged in LDS; no-max softmax in exp2 domain.
__global__ __launch_bounds__(256) void k_attn(const unsigned short* __restrict__ qws,
                                              const unsigned short* __restrict__ kws,
                                              const unsigned short* __restrict__ vtws,
                                              const unsigned short* __restrict__ bt,
                                              unsigned short* __restrict__ ows) {
  __shared__ unsigned short Kl[640 * 40];   // [n][32] pad->40
  __shared__ unsigned short Vl[32 * 648];   // [d][640] pad->648
  __shared__ unsigned short Pl[64 * 136];   // per-wave 16 rows of P (chunk cols 128)
  int bh = blockIdx.x, b = bh >> 2, h = bh & 3;
  int t = threadIdx.x, w = t >> 6, lane = t & 63, r16 = lane & 15, g = lane >> 4;
  const unsigned short* Kg = kws + (size_t)bh * 20480;
  const unsigned short* Vg = vtws + (size_t)bh * 20480;
  for (int it = 0; it < 10; ++it) {
    int v8 = it * 256 + t;
    int n = v8 >> 2, d0 = (v8 & 3) << 3;
    *reinterpret_cast<short8*>(&Kl[n * 40 + d0]) =
        *reinterpret_cast<const short8*>(Kg + n * 32 + d0);
  }
  for (int it = 0; it < 10; ++it) {
    int v8 = it * 256 + t;
    int d = v8 / 80, n0 = (v8 - d * 80) * 8;
    *reinterpret_cast<short8*>(&Vl[d * 648 + n0]) =
        *reinterpret_cast<const short8*>(Vg + d * 640 + n0);
  }
  __syncthreads();
  const unsigned short* Qg = qws + (size_t)bh * 20480;
  const unsigned short* bth = bt + (size_t)h * 409600;
  for (int qt = 0; qt < 10; ++qt) {
    int i0 = qt * 64 + w * 16;              // wave's 16 Q rows
    short8 qa = *reinterpret_cast<const short8*>(Qg + (i0 + r16) * 32 + g * 8);
    f32x4 oacc[2];
    oacc[0] = (f32x4){0.f, 0.f, 0.f, 0.f};
    oacc[1] = (f32x4){0.f, 0.f, 0.f, 0.f};
    float sp0 = 0.f, sp1 = 0.f, sp2 = 0.f, sp3 = 0.f;
    for (int c = 0; c < 5; ++c) {
      int j0 = c * 128;
      f32x4 s[8];
      f32x4 zz = (f32x4){0.f, 0.f, 0.f, 0.f};
#pragma unroll
      for (int jf = 0; jf < 8; ++jf) {
        short8 kb = *reinterpret_cast<short8*>(&Kl[(j0 + jf * 16 + r16) * 40 + g * 8]);
        s[jf] = MFMA16(qa, kb, zz);
      }
#pragma unroll
      for (int jf = 0; jf < 8; ++jf) {
        int j = j0 + jf * 16 + r16;
        ushort4 bv = *reinterpret_cast<const ushort4*>(bth + (size_t)j * 640 + i0 + 4 * g);
        float p0 = __builtin_amdgcn_exp2f(s[jf][0] + b2f(bv.x));
        float p1 = __builtin_amdgcn_exp2f(s[jf][1] + b2f(bv.y));
        float p2 = __builtin_amdgcn_exp2f(s[jf][2] + b2f(bv.z));
        float p3 = __builtin_amdgcn_exp2f(s[jf][3] + b2f(bv.w));
        sp0 += p0; sp1 += p1; sp2 += p2; sp3 += p3;
        int pr = w * 16 + 4 * g;
        int pc = jf * 16 + r16;
        Pl[(pr + 0) * 136 + pc] = f2b(p0);
        Pl[(pr + 1) * 136 + pc] = f2b(p1);
        Pl[(pr + 2) * 136 + pc] = f2b(p2);
        Pl[(pr + 3) * 136 + pc] = f2b(p3);
      }
      asm volatile("s_waitcnt lgkmcnt(0)" ::: "memory");  // P writes -> P reads (intra-wave)
#pragma unroll
      for (int ks = 0; ks < 4; ++ks) {
        short8 pa = *reinterpret_cast<short8*>(&Pl[(w * 16 + r16) * 136 + ks * 32 + g * 8]);
#pragma unroll
        for (int f = 0; f < 2; ++f) {
          short8 vb = *reinterpret_cast<short8*>(&Vl[(f * 16 + r16) * 648 + j0 + ks * 32 + g * 8]);
          oacc[f] = MFMA16(pa, vb, oacc[f]);
        }
      }
    }
#pragma unroll
    for (int m = 1; m < 16; m <<= 1) {
      sp0 += __shfl_xor(sp0, m, 64);
      sp1 += __shfl_xor(sp1, m, 64);
      sp2 += __shfl_xor(sp2, m, 64);
      sp3 += __shfl_xor(sp3, m, 64);
    }
    float rc0 = 1.f / sp0, rc1 = 1.f / sp1, rc2 = 1.f / sp2, rc3 = 1.f / sp3;
    size_t ob = ((size_t)b * 640 + i0 + 4 * g) * 128 + h * 32;
#pragma unroll
    for (int f = 0; f < 2; ++f) {
      ows[ob + 0 * 128 + f * 16 + r16] = f2b(oacc[f][0] * rc0);
      ows[ob + 1 * 128 + f * 16 + r16] = f2b(oacc[f][1] * rc1);
      ows[ob + 2 * 128 + f * 16 + r16] = f2b(oacc[f][2] * rc2);
      ows[ob + 3 * 128 + f * 16 + r16] = f2b(oacc[f][3] * rc3);
    }
  }
}

// ---------------------------------------------------------------- out proj
__global__ __launch_bounds__(256) void k_out(const unsigned short* __restrict__ ows,
                                             const float* __restrict__ wout,
                                             float* __restrict__ out) {
  __shared__ unsigned short Wl[128 * 136];
  int b = blockIdx.x, t = threadIdx.x;
  for (int it = 0; it < 16; ++it) {
    int g4 = it * 256 + t;                  // 4096 float4 of W_out
    int row = g4 >> 5, d0 = (g4 & 31) << 2;
    float4 w4 = *reinterpret_cast<const float4*>(wout + row * 128 + d0);
    ushort4 p;
    p.x = f2b(w4.x); p.y = f2b(w4.y); p.z = f2b(w4.z); p.w = f2b(w4.w);
    *reinterpret_cast<ushort4*>(&Wl[row * 136 + d0]) = p;
  }
  __syncthreads();
  int w = t >> 6, lane = t & 63, r16 = lane & 15, g = lane >> 4;
  const unsigned short* Ob = ows + (size_t)b * 640 * 128;
  float* outb = out + (size_t)b * 128 * 625;
  for (int tile = 0; tile < 10; ++tile) {
    int n0 = tile * 64;
    f32x4 acc[2][4];
#pragma unroll
    for (int mi = 0; mi < 2; ++mi)
#pragma unroll
      for (int f = 0; f < 4; ++f) acc[mi][f] = (f32x4){0.f, 0.f, 0.f, 0.f};
#pragma unroll
    for (int kk = 0; kk < 4; ++kk) {
      short8 bfr[4];
#pragma unroll
      for (int f = 0; f < 4; ++f)
        bfr[f] = *reinterpret_cast<const short8*>(Ob + (n0 + f * 16 + r16) * 128 + kk * 32 + g * 8);
#pragma unroll
      for (int mi = 0; mi < 2; ++mi) {
        short8 afr = *reinterpret_cast<short8*>(&Wl[(w * 32 + mi * 16 + r16) * 136 + kk * 32 + g * 8]);
#pragma unroll
        for (int f = 0; f < 4; ++f) acc[mi][f] = MFMA16(afr, bfr[f], acc[mi][f]);
      }
    }
#pragma unroll
    for (int mi = 0; mi < 2; ++mi)
#pragma unroll
      for (int f = 0; f < 4; ++f) {
        int n = n0 + f * 16 + r16;
        if (n < 625) {
          int dout = w * 32 + mi * 16 + 4 * g;
          outb[(dout + 0) * 625 + n] = acc[mi][f][0];
          outb[(dout + 1) * 625 + n] = acc[mi][f][1];
          outb[(dout + 2) * 625 + n] = acc[mi][f][2];
          outb[(dout + 3) * 625 + n] = acc[mi][f][3];
        }
      }
  }
}

// ---------------------------------------------------------------- launch
extern "C" void kernel_launch(void* const* d_in, const int* in_sizes, int n_in,
                              void* d_out, int out_size, void* d_ws, size_t ws_size,
                              hipStream_t stream) {
  const float* x     = (const float*)d_in[0];
  const float* wqkv  = (const float*)d_in[1];
  const float* wout  = (const float*)d_in[2];
  const float* table = (const float*)d_in[3];
  const int*   idx   = (const int*)d_in[4];
  float* out = (float*)d_out;

  char* ws = (char*)d_ws;  // requires ~171 MB
  unsigned short* qws  = (unsigned short*)(ws);
  unsigned short* kws  = (unsigned short*)(ws + 41943040);
  unsigned short* vtws = (unsigned short*)(ws + 83886080);
  unsigned short* ows  = (unsigned short*)(ws + 125829120);
  unsigned short* bt   = (unsigned short*)(ws + 167772160);

  k_bias<<<dim3(1600), dim3(256), 0, stream>>>(table, idx, bt);
  k_qkv<<<dim3(256), dim3(256), 0, stream>>>(x, wqkv, qws, kws, vtws);
  k_attn<<<dim3(1024), dim3(256), 0, stream>>>(qws, kws, vtws, bt, ows);
  k_out<<<dim3(256), dim3(256), 0, stream>>>(ows, wout, out);
}